// Round 1
// baseline (1608.546 us; speedup 1.0000x reference)
//
#include <hip/hip_runtime.h>

typedef __attribute__((ext_vector_type(8))) short bf16x8;
typedef __attribute__((ext_vector_type(4))) float f32x4;
typedef __attribute__((ext_vector_type(4))) unsigned short us4;

#define N_HEAD 16
#define SEQ 2048

__device__ __forceinline__ unsigned short f2bf(float f) {
  union { float f; unsigned u; } v; v.f = f;
  unsigned r = v.u + 0x7fffu + ((v.u >> 16) & 1u);
  return (unsigned short)(r >> 16);
}

// ---------------- Kernel A: fused QKV projection (y = x @ W^T + b) ----------
// z=0: q (scaled by 0.125) -> [b,h,s,d] bf16
// z=1: k                   -> [b,h,s,d] bf16
// z=2: v                   -> [b,h,d,s] bf16 (transposed for PV B-operand)
__global__ __launch_bounds__(256, 2)
void qkv_gemm(const float* __restrict__ x,
              const float* __restrict__ wq, const float* __restrict__ bq,
              const float* __restrict__ wk, const float* __restrict__ bk,
              const float* __restrict__ wv, const float* __restrict__ bv,
              unsigned short* __restrict__ qws,
              unsigned short* __restrict__ kws,
              unsigned short* __restrict__ vtws)
{
  // LDS tiles 128 rows x 32 k, bf16, row stride 40 (80B: b128-aligned, 2-way banks)
  __shared__ unsigned short As[128 * 40];
  __shared__ unsigned short Bs[128 * 40];

  const int tid  = threadIdx.x;
  const int wave = tid >> 6, lane = tid & 63;
  const int quad = lane >> 4, lrow = lane & 15;
  const int wm = wave >> 1, wn = wave & 1;
  const int m0 = blockIdx.x * 128, n0 = blockIdx.y * 128;
  const int z = blockIdx.z;

  const float* W;  const float* bvec;
  if (z == 0)      { W = wq; bvec = bq; }
  else if (z == 1) { W = wk; bvec = bk; }
  else             { W = wv; bvec = bv; }

  f32x4 acc[4][4];
  #pragma unroll
  for (int mi = 0; mi < 4; ++mi)
    #pragma unroll
    for (int ni = 0; ni < 4; ++ni)
      acc[mi][ni] = (f32x4){0.f, 0.f, 0.f, 0.f};

  for (int k0 = 0; k0 < 1024; k0 += 32) {
    __syncthreads();
    #pragma unroll
    for (int r = 0; r < 4; ++r) {
      int idx = tid + r * 256;          // 0..1023
      int row = idx >> 3, seg = idx & 7;
      float4 xa = *(const float4*)(x + (size_t)(m0 + row) * 1024 + k0 + seg * 4);
      float4 xb = *(const float4*)(W + (size_t)(n0 + row) * 1024 + k0 + seg * 4);
      us4 ua = { f2bf(xa.x), f2bf(xa.y), f2bf(xa.z), f2bf(xa.w) };
      us4 ub = { f2bf(xb.x), f2bf(xb.y), f2bf(xb.z), f2bf(xb.w) };
      *(us4*)&As[row * 40 + seg * 4] = ua;
      *(us4*)&Bs[row * 40 + seg * 4] = ub;
    }
    __syncthreads();

    bf16x8 a[4], b[4];
    #pragma unroll
    for (int mi = 0; mi < 4; ++mi)
      a[mi] = *(const bf16x8*)&As[(wm * 64 + mi * 16 + lrow) * 40 + quad * 8];
    #pragma unroll
    for (int ni = 0; ni < 4; ++ni)
      b[ni] = *(const bf16x8*)&Bs[(wn * 64 + ni * 16 + lrow) * 40 + quad * 8];
    #pragma unroll
    for (int mi = 0; mi < 4; ++mi)
      #pragma unroll
      for (int ni = 0; ni < 4; ++ni)
        acc[mi][ni] = __builtin_amdgcn_mfma_f32_16x16x32_bf16(a[mi], b[ni], acc[mi][ni], 0, 0, 0);
  }

  float badd[4];
  #pragma unroll
  for (int ni = 0; ni < 4; ++ni) badd[ni] = bvec[n0 + wn * 64 + ni * 16 + lrow];

  #pragma unroll
  for (int mi = 0; mi < 4; ++mi) {
    #pragma unroll
    for (int ni = 0; ni < 4; ++ni) {
      int j = n0 + wn * 64 + ni * 16 + lrow;   // output feature
      int hh = j >> 6, dd = j & 63;
      #pragma unroll
      for (int r = 0; r < 4; ++r) {
        int i = m0 + wm * 64 + mi * 16 + quad * 4 + r;  // token row
        int bb = i >> 11, ss = i & 2047;
        float y = acc[mi][ni][r] + badd[ni];
        if (z == 0)
          qws[(((size_t)(bb * 16 + hh)) * 2048 + ss) * 64 + dd] = f2bf(y * 0.125f);
        else if (z == 1)
          kws[(((size_t)(bb * 16 + hh)) * 2048 + ss) * 64 + dd] = f2bf(y);
        else
          vtws[(((size_t)(bb * 16 + hh)) * 64 + dd) * 2048 + ss] = f2bf(y);
      }
    }
  }
}

// ---------------- Kernel B: fused QK^T + bias + mask + softmax + weights + PV
// One block per (bh, 16-row q strip). 4 waves; wave w owns cols [512w,512w+512).
// Full 16x2048 logit strip in registers (32 f32x4 acc / lane / wave).
__global__ __launch_bounds__(256, 2)
void attn(const unsigned short* __restrict__ qws,
          const unsigned short* __restrict__ kws,
          const unsigned short* __restrict__ vtws,
          const float* __restrict__ bias,
          const int* __restrict__ mask,
          float* __restrict__ out)
{
  const int tid  = threadIdx.x;
  const int wave = tid >> 6, lane = tid & 63;
  const int quad = lane >> 4, lrow = lane & 15;
  const int q0 = blockIdx.x * 16;
  const int bh = blockIdx.y;            // b*16+h
  const int h  = bh & 15;
  const int cb = wave * 512;

  const unsigned short* qh  = qws  + (size_t)bh * SEQ * 64;
  const unsigned short* kh  = kws  + (size_t)bh * SEQ * 64;
  const unsigned short* vth = vtws + (size_t)bh * 64 * SEQ;
  float* out_o = out;
  float* out_w = out + (size_t)2 * N_HEAD * SEQ * 64;

  __shared__ float red[4][16];
  __shared__ unsigned short pbuf[4][2][16][32];  // per-wave C->A layout bounce
  __shared__ float obuf[4][16][64];              // cross-wave PV reduce

  // Q fragments (A-operand): lane -> A[m=lrow][k=quad*8+j], 2 k-chunks of 32
  bf16x8 aq[2];
  #pragma unroll
  for (int ks = 0; ks < 2; ++ks)
    aq[ks] = *(const bf16x8*)(qh + (size_t)(q0 + lrow) * 64 + ks * 32 + quad * 8);

  // ---- QK^T * scale + bias, mask -> S (C-layout: col=lrow, row=quad*4+reg)
  f32x4 S[32];
  #pragma unroll
  for (int t = 0; t < 32; ++t) {
    int col0 = cb + t * 16;
    f32x4 c = (f32x4){0.f, 0.f, 0.f, 0.f};
    #pragma unroll
    for (int ks = 0; ks < 2; ++ks) {
      bf16x8 bk8 = *(const bf16x8*)(kh + (size_t)(col0 + lrow) * 64 + ks * 32 + quad * 8);
      c = __builtin_amdgcn_mfma_f32_16x16x32_bf16(aq[ks], bk8, c, 0, 0, 0);
    }
    int mycol = col0 + lrow;
    #pragma unroll
    for (int r = 0; r < 4; ++r) {
      int grow = q0 + quad * 4 + r;
      float bb = bias[((size_t)h * SEQ + grow) * SEQ + mycol];
      int   mm = mask[(size_t)grow * SEQ + mycol];
      c[r] = (mm == 0) ? -1e9f : (c[r] + bb);
    }
    S[t] = c;
  }

  // ---- row max (16 lanes of a quad share rows quad*4+0..3)
  float rmax[4];
  #pragma unroll
  for (int r = 0; r < 4; ++r) {
    float m = S[0][r];
    #pragma unroll
    for (int t = 1; t < 32; ++t) m = fmaxf(m, S[t][r]);
    #pragma unroll
    for (int d = 1; d < 16; d <<= 1) m = fmaxf(m, __shfl_xor(m, d));
    rmax[r] = m;
  }
  if (lrow == 0) {
    #pragma unroll
    for (int r = 0; r < 4; ++r) red[wave][quad * 4 + r] = rmax[r];
  }
  __syncthreads();
  float M[4];
  #pragma unroll
  for (int r = 0; r < 4; ++r) {
    int rr = quad * 4 + r;
    M[r] = fmaxf(fmaxf(red[0][rr], red[1][rr]), fmaxf(red[2][rr], red[3][rr]));
  }
  __syncthreads();   // red reused for sums

  // ---- exp + row sum
  float rsum[4] = {0.f, 0.f, 0.f, 0.f};
  #pragma unroll
  for (int t = 0; t < 32; ++t) {
    #pragma unroll
    for (int r = 0; r < 4; ++r) {
      float e = exp2f((S[t][r] - M[r]) * 1.44269504f);
      S[t][r] = e;
      rsum[r] += e;
    }
  }
  #pragma unroll
  for (int r = 0; r < 4; ++r) {
    float s = rsum[r];
    #pragma unroll
    for (int d = 1; d < 16; d <<= 1) s += __shfl_xor(s, d);
    rsum[r] = s;
  }
  if (lrow == 0) {
    #pragma unroll
    for (int r = 0; r < 4; ++r) red[wave][quad * 4 + r] = rsum[r];
  }
  __syncthreads();
  float inv[4];
  #pragma unroll
  for (int r = 0; r < 4; ++r) {
    int rr = quad * 4 + r;
    inv[r] = 1.0f / (red[0][rr] + red[1][rr] + red[2][rr] + red[3][rr]);
  }

  // ---- normalize + write attention weights (fp32, second output)
  float* wrow = out_w + ((size_t)bh * SEQ + q0) * SEQ;
  #pragma unroll
  for (int t = 0; t < 32; ++t) {
    int mycol = cb + t * 16 + lrow;
    #pragma unroll
    for (int r = 0; r < 4; ++r) {
      float w = S[t][r] * inv[r];
      S[t][r] = w;
      wrow[(size_t)(quad * 4 + r) * SEQ + mycol] = w;
    }
  }

  // ---- PV: per 32-col chunk, bounce w through LDS (C-layout -> A-layout)
  f32x4 O[4];
  #pragma unroll
  for (int n = 0; n < 4; ++n) O[n] = (f32x4){0.f, 0.f, 0.f, 0.f};

  #pragma unroll
  for (int c = 0; c < 16; ++c) {
    const int pb = c & 1;
    #pragma unroll
    for (int tt = 0; tt < 2; ++tt) {
      #pragma unroll
      for (int r = 0; r < 4; ++r)
        pbuf[wave][pb][quad * 4 + r][tt * 16 + lrow] = f2bf(S[2 * c + tt][r]);
    }
    asm volatile("s_waitcnt lgkmcnt(0)" ::: "memory");  // wave-internal LDS RAW
    bf16x8 aw = *(const bf16x8*)&pbuf[wave][pb][lrow][quad * 8];
    #pragma unroll
    for (int n = 0; n < 4; ++n) {
      bf16x8 v8 = *(const bf16x8*)(vth + (size_t)(n * 16 + lrow) * SEQ + cb + c * 32 + quad * 8);
      O[n] = __builtin_amdgcn_mfma_f32_16x16x32_bf16(aw, v8, O[n], 0, 0, 0);
    }
  }

  // ---- cross-wave reduce of O, write first output
  #pragma unroll
  for (int n = 0; n < 4; ++n)
    #pragma unroll
    for (int r = 0; r < 4; ++r)
      obuf[wave][quad * 4 + r][n * 16 + lrow] = O[n][r];
  __syncthreads();
  #pragma unroll
  for (int e = 0; e < 4; ++e) {
    int idx = e * 256 + tid;
    int row = idx >> 6, dd = idx & 63;
    float v = obuf[0][row][dd] + obuf[1][row][dd] + obuf[2][row][dd] + obuf[3][row][dd];
    out_o[((size_t)bh * SEQ + q0 + row) * 64 + dd] = v;
  }
}

extern "C" void kernel_launch(void* const* d_in, const int* in_sizes, int n_in,
                              void* d_out, int out_size, void* d_ws, size_t ws_size,
                              hipStream_t stream) {
  const float* x    = (const float*)d_in[0];
  const float* bias = (const float*)d_in[1];
  const int*   mask = (const int*)d_in[2];
  const float* wq   = (const float*)d_in[3];
  const float* bq   = (const float*)d_in[4];
  const float* wk   = (const float*)d_in[5];
  const float* bk   = (const float*)d_in[6];
  const float* wv   = (const float*)d_in[7];
  const float* bv   = (const float*)d_in[8];

  unsigned short* qws  = (unsigned short*)d_ws;           // 2*16*2048*64 bf16 = 8 MB
  unsigned short* kws  = qws + (size_t)4194304;           // 8 MB
  unsigned short* vtws = kws + (size_t)4194304;           // 8 MB (transposed V)
  float* out = (float*)d_out;

  // QKV projections: M=4096, N=1024 per weight, K=1024; z selects q/k/v
  qkv_gemm<<<dim3(32, 8, 3), 256, 0, stream>>>(x, wq, bq, wk, bk, wv, bv,
                                               qws, kws, vtws);
  // Attention: 128 q-strips x 32 (b,h)
  attn<<<dim3(128, 32), 256, 0, stream>>>(qws, kws, vtws, bias, mask, out);
}